// Round 7
// baseline (294.952 us; speedup 1.0000x reference)
//
#include <hip/hip_runtime.h>
#include <math.h>

#define W_LEN 1024
#define BSZ 16
#define EMBED 512
#define NHEADS 8
#define HEAD_DIM 64
#define TOKENS (W_LEN * BSZ)
#define LN_EPS 1e-5f

typedef __bf16 bf16_t;
typedef bf16_t bf16x8 __attribute__((ext_vector_type(8)));
typedef float f32x4 __attribute__((ext_vector_type(4)));

__device__ inline unsigned short f2bf(float f) {
    unsigned int u = __float_as_uint(f);
    u += 0x7fffu + ((u >> 16) & 1u);   // round-to-nearest-even
    return (unsigned short)(u >> 16);
}

// pack two f32 -> bf16x2 by TRUNCATION, one v_perm_b32
__device__ __forceinline__ unsigned pkbf_trunc(float lo, float hi) {
    return __builtin_amdgcn_perm(__float_as_uint(hi), __float_as_uint(lo), 0x07060302u);
}

// async global->LDS, 16 B per lane; LDS dest is wave-uniform base + lane*16
__device__ __forceinline__ void async16(const void* g, void* l) {
    __builtin_amdgcn_global_load_lds(
        (__attribute__((address_space(1))) void*)g,
        (__attribute__((address_space(3))) void*)l, 16, 0, 0);
}

// ---------------------------------------------------------------- fp32 -> bf16 weight casts (merged)
__global__ __launch_bounds__(256) void cvt_weights(const float* __restrict__ in_w,
                                                   const float* __restrict__ out_w,
                                                   unsigned short* __restrict__ wib,
                                                   unsigned short* __restrict__ wob) {
    const int N1 = 3 * EMBED * EMBED;
    int i = (blockIdx.x * 256 + threadIdx.x) * 4;
    const float* src; unsigned short* dst; int off;
    if (i < N1) { src = in_w;  dst = wib; off = i; }
    else        { src = out_w; dst = wob; off = i - N1; }
    float4 f = *(const float4*)(src + off);
    uint2 p;
    p.x = (unsigned)f2bf(f.x) | ((unsigned)f2bf(f.y) << 16);
    p.y = (unsigned)f2bf(f.z) | ((unsigned)f2bf(f.w) << 16);
    *(uint2*)(dst + off) = p;
}

// ---------------------------------------------------------------- LayerNorm -> bf16
__global__ __launch_bounds__(256) void ln_kernel(
    const float* __restrict__ feat, const float* __restrict__ g,
    const float* __restrict__ b, unsigned short* __restrict__ xln)
{
    int tid   = threadIdx.x;
    int token = blockIdx.x * 4 + (tid >> 6);
    int lane  = tid & 63;
    const float* row = feat + (size_t)token * EMBED;

    float x[8];
    *(float4*)(x)     = *(const float4*)(row + lane * 4);
    *(float4*)(x + 4) = *(const float4*)(row + 256 + lane * 4);

    float sum = 0.f, ssq = 0.f;
#pragma unroll
    for (int i = 0; i < 8; i++) { sum += x[i]; ssq += x[i] * x[i]; }
#pragma unroll
    for (int off = 32; off > 0; off >>= 1) {
        sum += __shfl_xor(sum, off, 64);
        ssq += __shfl_xor(ssq, off, 64);
    }
    float mu  = sum * (1.0f / EMBED);
    float var = ssq * (1.0f / EMBED) - mu * mu;
    float rs  = rsqrtf(var + LN_EPS);

    float gg[8], bb[8], o[8];
    *(float4*)(gg)     = *(const float4*)(g + lane * 4);
    *(float4*)(gg + 4) = *(const float4*)(g + 256 + lane * 4);
    *(float4*)(bb)     = *(const float4*)(b + lane * 4);
    *(float4*)(bb + 4) = *(const float4*)(b + 256 + lane * 4);
#pragma unroll
    for (int i = 0; i < 8; i++) o[i] = (x[i] - mu) * rs * gg[i] + bb[i];

    unsigned short* orow = xln + (size_t)token * EMBED;
    uint2 lo, hi;
    lo.x = (unsigned)f2bf(o[0]) | ((unsigned)f2bf(o[1]) << 16);
    lo.y = (unsigned)f2bf(o[2]) | ((unsigned)f2bf(o[3]) << 16);
    hi.x = (unsigned)f2bf(o[4]) | ((unsigned)f2bf(o[5]) << 16);
    hi.y = (unsigned)f2bf(o[6]) | ((unsigned)f2bf(o[7]) << 16);
    *(uint2*)(orow + lane * 4)       = lo;
    *(uint2*)(orow + 256 + lane * 4) = hi;
}

// ---------------------------------------------------------------- MFMA GEMM core
// 128x128 tile, 4 waves each 64x64, BK=64 (two stride-32 LDS pairs),
// global_load_lds x16, 32 MFMA per barrier-pair.
__device__ __forceinline__ void gemm_core(const unsigned short* __restrict__ A,
                                          const unsigned short* __restrict__ Bt,
                                          int i0, int j0,
                                          unsigned short (*As0)[32], unsigned short (*As1)[32],
                                          unsigned short (*Bs0)[32], unsigned short (*Bs1)[32],
                                          f32x4 acc[4][4])
{
    int t = threadIdx.x;
    int wave = t >> 6, lane = t & 63, quad = lane >> 4, l16 = lane & 15;
    int wm = (wave >> 1) * 64, wn = (wave & 1) * 64;
    int srow = t >> 2, scol = (t & 3) * 8;
    const unsigned short* ga0 = A  + (size_t)(i0 + srow) * EMBED + scol;
    const unsigned short* ga1 = A  + (size_t)(i0 + srow + 64) * EMBED + scol;
    const unsigned short* gb0 = Bt + (size_t)(j0 + srow) * EMBED + scol;
    const unsigned short* gb1 = Bt + (size_t)(j0 + srow + 64) * EMBED + scol;

    for (int k0 = 0; k0 < EMBED; k0 += 64) {
        __syncthreads();                    // prior-iter readers done
        async16(ga0 + k0,      &As0[srow][scol]);
        async16(ga1 + k0,      &As0[srow + 64][scol]);
        async16(gb0 + k0,      &Bs0[srow][scol]);
        async16(gb1 + k0,      &Bs0[srow + 64][scol]);
        async16(ga0 + k0 + 32, &As1[srow][scol]);
        async16(ga1 + k0 + 32, &As1[srow + 64][scol]);
        async16(gb0 + k0 + 32, &Bs1[srow][scol]);
        async16(gb1 + k0 + 32, &Bs1[srow + 64][scol]);
        __syncthreads();                    // barrier drains the DMA

#pragma unroll
        for (int h = 0; h < 2; h++) {
            unsigned short (*Ah)[32] = h ? As1 : As0;
            unsigned short (*Bh)[32] = h ? Bs1 : Bs0;
            bf16x8 af[4], bfr[4];
#pragma unroll
            for (int m = 0; m < 4; m++) af[m]  = *(const bf16x8*)&Ah[wm + m * 16 + l16][quad * 8];
#pragma unroll
            for (int n = 0; n < 4; n++) bfr[n] = *(const bf16x8*)&Bh[wn + n * 16 + l16][quad * 8];
#pragma unroll
            for (int m = 0; m < 4; m++)
#pragma unroll
                for (int n = 0; n < 4; n++)
                    acc[m][n] = __builtin_amdgcn_mfma_f32_16x16x32_bf16(af[m], bfr[n], acc[m][n], 0, 0, 0);
        }
    }
}

// ---------------------------------------------------------------- QKV GEMM (bf16 out, scatter)
// q,k,v all [bh][w][d]; 16 l16-lanes cover 32 contiguous B -> sector-clean.
// q pre-scaled by 0.125*log2(e) so attention can use exp2 directly.
__global__ __launch_bounds__(256) void qkv_gemm_mfma(
    const unsigned short* __restrict__ A, const unsigned short* __restrict__ Bt,
    const float* __restrict__ bias, unsigned short* __restrict__ qo,
    unsigned short* __restrict__ ko, unsigned short* __restrict__ vo)
{
    __shared__ unsigned short As0[128][32], As1[128][32];
    __shared__ unsigned short Bs0[128][32], Bs1[128][32];
    f32x4 acc[4][4];
    const f32x4 z = {0.f, 0.f, 0.f, 0.f};
#pragma unroll
    for (int m = 0; m < 4; m++)
#pragma unroll
        for (int n = 0; n < 4; n++) acc[m][n] = z;

    int i0 = blockIdx.x * 128, j0 = blockIdx.y * 128;
    gemm_core(A, Bt, i0, j0, As0, As1, Bs0, Bs1, acc);

    int t = threadIdx.x, wave = t >> 6, lane = t & 63, quad = lane >> 4, l16 = lane & 15;
    int wm = (wave >> 1) * 64, wn = (wave & 1) * 64;
    int seg = j0 >> 9;                       // tile lies wholly in one of q/k/v
    unsigned short* outp = (seg == 0) ? qo : ((seg == 1) ? ko : vo);
    float scale = (seg == 0) ? 0.18033688f : 1.0f;   // 0.125 * log2(e)

    float bj[4]; int hh[4], dd[4];
#pragma unroll
    for (int n = 0; n < 4; n++) {
        int j = j0 + wn + n * 16 + l16;
        bj[n] = bias[j];
        hh[n] = (j >> 6) & 7;
        dd[n] = j & 63;
    }
#pragma unroll
    for (int m = 0; m < 4; m++)
#pragma unroll
        for (int r = 0; r < 4; r++) {
            int token = i0 + wm + m * 16 + quad * 4 + r;
            int w  = token >> 4;
            int b_ = token & 15;
#pragma unroll
            for (int n = 0; n < 4; n++) {
                size_t idx = (((size_t)(b_ * NHEADS + hh[n]) * W_LEN + w) << 6) + dd[n];
                outp[idx] = f2bf((acc[m][n][r] + bj[n]) * scale);
            }
        }
}

// ---------------------------------------------------------------- out-proj GEMM + residual
__global__ __launch_bounds__(256) void out_gemm_mfma(
    const unsigned short* __restrict__ A, const unsigned short* __restrict__ Bt,
    const float* __restrict__ bias, const float* __restrict__ feat,
    float* __restrict__ out)
{
    __shared__ unsigned short As0[128][32], As1[128][32];
    __shared__ unsigned short Bs0[128][32], Bs1[128][32];
    f32x4 acc[4][4];
    const f32x4 z = {0.f, 0.f, 0.f, 0.f};
#pragma unroll
    for (int m = 0; m < 4; m++)
#pragma unroll
        for (int n = 0; n < 4; n++) acc[m][n] = z;

    int i0 = blockIdx.x * 128, j0 = blockIdx.y * 128;
    gemm_core(A, Bt, i0, j0, As0, As1, Bs0, Bs1, acc);

    int t = threadIdx.x, wave = t >> 6, lane = t & 63, quad = lane >> 4, l16 = lane & 15;
    int wm = (wave >> 1) * 64, wn = (wave & 1) * 64;

    float bj[4];
#pragma unroll
    for (int n = 0; n < 4; n++) bj[n] = bias[j0 + wn + n * 16 + l16];
#pragma unroll
    for (int m = 0; m < 4; m++)
#pragma unroll
        for (int r = 0; r < 4; r++) {
            int token = i0 + wm + m * 16 + quad * 4 + r;
#pragma unroll
            for (int n = 0; n < 4; n++) {
                int col = j0 + wn + n * 16 + l16;
                size_t idx = (size_t)token * EMBED + col;
                out[idx] = acc[m][n][r] + bj[n] + feat[idx];
            }
        }
}

// ---------------------------------------------------------------- flash attention, MFMA, S^T form
// grid = (bh=128, qtile=8): q-tiles of a bh colocate per XCD, K/V L2-resident.
// K-fragments load DIRECTLY from global into registers (contiguous 16 B per
// lane, 64-B segment coalesced, L2-hit), software-prefetched one tile ahead —
// K never touches LDS. V transposed in-LDS via v_perm pair-pack. P and O
// packed to bf16 by v_perm truncation. Static softmax via exp2 (q pre-scaled
// by 0.125*log2e in QKV; scores bounded, no overflow).
__global__ __launch_bounds__(256, 4) void attn_mfma(
    const unsigned short* __restrict__ q, const unsigned short* __restrict__ k,
    const unsigned short* __restrict__ v, unsigned short* __restrict__ outp)
{
    __shared__ union {
        unsigned short Q[128][72];                 // only during Q-frag hoist
        struct {
            unsigned short V[64][72];              // [d][kj] (transposed in LDS)
            unsigned short P[4][32][72];           // per-wave P[qrow][kj]
        } s;
    } sm;

    int t = threadIdx.x, wave = t >> 6, lane = t & 63, quad = lane >> 4, l16 = lane & 15;
    int bh = blockIdx.x;
    int q0 = blockIdx.y * 128;
    const unsigned short* qp = q + ((size_t)bh * W_LEN + q0) * HEAD_DIM;
    const unsigned short* kp = k + (size_t)bh * W_LEN * HEAD_DIM;
    const unsigned short* vp = v + (size_t)bh * W_LEN * HEAD_DIM;

    // stage Q (128x64) then hoist this wave's Q B-frags into registers
    {
        int qr = t >> 1, qc0 = (t & 1) * 32;
#pragma unroll
        for (int c = 0; c < 32; c += 8)
            *(uint4*)&sm.Q[qr][qc0 + c] = *(const uint4*)(qp + (size_t)qr * 64 + qc0 + c);
    }
    __syncthreads();
    bf16x8 qf[2][2];                               // [nt][ks]
#pragma unroll
    for (int nt = 0; nt < 2; nt++)
#pragma unroll
        for (int ks = 0; ks < 2; ks++)
            qf[nt][ks] = *(const bf16x8*)&sm.Q[wave * 32 + nt * 16 + l16][ks * 32 + quad * 8];
    __syncthreads();                               // all waves done with Q region

    float l_st[2] = {0.f, 0.f};
    f32x4 o_acc[4][2];                             // [mtd(d)][nt(qrow)]
    const f32x4 z = {0.f, 0.f, 0.f, 0.f};
#pragma unroll
    for (int m = 0; m < 4; m++)
#pragma unroll
        for (int n = 0; n < 2; n++) o_acc[m][n] = z;

    // K-frag lane base: A-frag element = K[mt*16+l16][ks*32+quad*8 + j]
    const unsigned short* kfp = kp + (size_t)l16 * HEAD_DIM + quad * 8;

    // prefetch tile 0: K-frags into registers, V rows into registers
    bf16x8 kf[4][2];
#pragma unroll
    for (int mt = 0; mt < 4; mt++)
#pragma unroll
        for (int ks = 0; ks < 2; ks++)
            kf[mt][ks] = *(const bf16x8*)(kfp + (size_t)mt * 16 * HEAD_DIM + ks * 32);

    int j2 = t & 31, vc = (t >> 5) * 8;             // V staging: kj-pair, d-chunk
    union { uint4 u; unsigned w[4]; } vg0, vg1;
    vg0.u = *(const uint4*)(vp + (size_t)(2 * j2) * 64 + vc);
    vg1.u = *(const uint4*)(vp + (size_t)(2 * j2 + 1) * 64 + vc);

    for (int kt = 0; kt < W_LEN; kt += 64) {
        __syncthreads();                           // prior-iter V/P readers done
        // publish V^T[d][kj] via v_perm pair-pack (lossless repack)
#pragma unroll
        for (int w2 = 0; w2 < 4; w2++) {
            unsigned lo = __builtin_amdgcn_perm(vg1.w[w2], vg0.w[w2], 0x05040100u);
            unsigned hi = __builtin_amdgcn_perm(vg1.w[w2], vg0.w[w2], 0x07060302u);
            *(unsigned*)&sm.s.V[vc + 2 * w2][2 * j2]     = lo;
            *(unsigned*)&sm.s.V[vc + 2 * w2 + 1][2 * j2] = hi;
        }
        __syncthreads();

        int ktn = (kt + 64 < W_LEN) ? kt + 64 : kt;
        // prefetch next V (overlaps with MFMA below)
        vg0.u = *(const uint4*)(vp + (size_t)(ktn + 2 * j2) * 64 + vc);
        vg1.u = *(const uint4*)(vp + (size_t)(ktn + 2 * j2 + 1) * 64 + vc);

        // ---- S^T = K * Q^T : s[mt][nt], rows=kj, cols=qrow (K from registers)
        f32x4 s[4][2];
#pragma unroll
        for (int mt = 0; mt < 4; mt++)
#pragma unroll
            for (int nt = 0; nt < 2; nt++) s[mt][nt] = z;
#pragma unroll
        for (int ks = 0; ks < 2; ks++)
#pragma unroll
            for (int mt = 0; mt < 4; mt++)
#pragma unroll
                for (int nt = 0; nt < 2; nt++)
                    s[mt][nt] = __builtin_amdgcn_mfma_f32_16x16x32_bf16(kf[mt][ks], qf[nt][ks], s[mt][nt], 0, 0, 0);

        // reload K-frags for next tile (consumed above; ~full iter to cover L2 latency)
        {
            const unsigned short* kfn = kfp + (size_t)ktn * HEAD_DIM;
#pragma unroll
            for (int mt = 0; mt < 4; mt++)
#pragma unroll
                for (int ks = 0; ks < 2; ks++)
                    kf[mt][ks] = *(const bf16x8*)(kfn + (size_t)mt * 16 * HEAD_DIM + ks * 32);
        }

        // ---- static softmax: p = 2^s (q pre-scaled by log2e), row-sum
#pragma unroll
        for (int nt = 0; nt < 2; nt++) {
            float sum = 0.f;
#pragma unroll
            for (int mt = 0; mt < 4; mt++)
#pragma unroll
                for (int r = 0; r < 4; r++) {
                    float p = exp2f(s[mt][nt][r]);
                    s[mt][nt][r] = p;
                    sum += p;
                }
            sum += __shfl_xor(sum, 16, 64);
            sum += __shfl_xor(sum, 32, 64);
            l_st[nt] += sum;
        }

        // ---- P -> LDS row-major [qrow][kj]; v_perm truncation packs
#pragma unroll
        for (int nt = 0; nt < 2; nt++)
#pragma unroll
            for (int mt = 0; mt < 4; mt++) {
                uint2 pk;
                pk.x = pkbf_trunc(s[mt][nt][0], s[mt][nt][1]);
                pk.y = pkbf_trunc(s[mt][nt][2], s[mt][nt][3]);
                *(uint2*)&sm.s.P[wave][nt * 16 + l16][mt * 16 + quad * 4] = pk;
            }
        asm volatile("s_waitcnt lgkmcnt(0)" ::: "memory");   // wave-private P

        // ---- O^T += V^T * P^T
#pragma unroll
        for (int ks = 0; ks < 2; ks++) {
            bf16x8 vf[4], pf[2];
#pragma unroll
            for (int mtd = 0; mtd < 4; mtd++)
                vf[mtd] = *(const bf16x8*)&sm.s.V[mtd * 16 + l16][ks * 32 + quad * 8];
#pragma unroll
            for (int nt = 0; nt < 2; nt++)
                pf[nt] = *(const bf16x8*)&sm.s.P[wave][nt * 16 + l16][ks * 32 + quad * 8];
#pragma unroll
            for (int mtd = 0; mtd < 4; mtd++)
#pragma unroll
                for (int nt = 0; nt < 2; nt++)
                    o_acc[mtd][nt] = __builtin_amdgcn_mfma_f32_16x16x32_bf16(vf[mtd], pf[nt], o_acc[mtd][nt], 0, 0, 0);
        }
    }

    // ---- epilogue: O^T cols=qrow (lane), rows=d (regs): uint2 stores
    int b_ = bh >> 3, h = bh & 7;
#pragma unroll
    for (int nt = 0; nt < 2; nt++) {
        int w = q0 + wave * 32 + nt * 16 + l16;
        int token = w * BSZ + b_;
        float inv = 1.0f / l_st[nt];
#pragma unroll
        for (int mtd = 0; mtd < 4; mtd++) {
            uint2 pk;
            pk.x = pkbf_trunc(o_acc[mtd][nt][0] * inv, o_acc[mtd][nt][1] * inv);
            pk.y = pkbf_trunc(o_acc[mtd][nt][2] * inv, o_acc[mtd][nt][3] * inv);
            *(uint2*)(outp + (size_t)token * EMBED + h * HEAD_DIM + mtd * 16 + quad * 4) = pk;
        }
    }
}

// ---------------------------------------------------------------- launch
extern "C" void kernel_launch(void* const* d_in, const int* in_sizes, int n_in,
                              void* d_out, int out_size, void* d_ws, size_t ws_size,
                              hipStream_t stream) {
    const float* feat  = (const float*)d_in[0];
    const float* in_w  = (const float*)d_in[1];
    const float* in_b  = (const float*)d_in[2];
    const float* out_w = (const float*)d_in[3];
    const float* out_b = (const float*)d_in[4];
    const float* ln_g  = (const float*)d_in[5];
    const float* ln_b  = (const float*)d_in[6];
    float* out = (float*)d_out;

    char* ws = (char*)d_ws;
    const size_t SZB = (size_t)TOKENS * EMBED * sizeof(unsigned short);   // 16.8 MB
    unsigned short* xln = (unsigned short*)ws;
    unsigned short* qb  = (unsigned short*)(ws + SZB);
    unsigned short* kb  = (unsigned short*)(ws + 2 * SZB);
    unsigned short* vb  = (unsigned short*)(ws + 3 * SZB);
    unsigned short* ao  = (unsigned short*)(ws + 4 * SZB);
    unsigned short* wib = (unsigned short*)(ws + 5 * SZB);
    unsigned short* wob = (unsigned short*)(ws + 5 * SZB +
                                            (size_t)3 * EMBED * EMBED * sizeof(unsigned short));

    cvt_weights<<<(4 * EMBED * EMBED) / 1024, 256, 0, stream>>>(in_w, out_w, wib, wob);
    ln_kernel<<<TOKENS / 4, 256, 0, stream>>>(feat, ln_g, ln_b, xln);
    qkv_gemm_mfma<<<dim3(TOKENS / 128, (3 * EMBED) / 128), 256, 0, stream>>>(
        xln, wib, in_b, qb, kb, vb);
    attn_mfma<<<dim3(BSZ * NHEADS, W_LEN / 128), 256, 0, stream>>>(qb, kb, vb, ao);
    out_gemm_mfma<<<dim3(TOKENS / 128, EMBED / 128), 256, 0, stream>>>(
        ao, wob, out_b, feat, out);
}

// Round 8
// 216.079 us; speedup vs baseline: 1.3650x; 1.3650x over previous
//
#include <hip/hip_runtime.h>
#include <math.h>

#define W_LEN 1024
#define BSZ 16
#define EMBED 512
#define NHEADS 8
#define HEAD_DIM 64
#define TOKENS (W_LEN * BSZ)
#define LN_EPS 1e-5f

typedef __bf16 bf16_t;
typedef bf16_t bf16x8 __attribute__((ext_vector_type(8)));
typedef float f32x4 __attribute__((ext_vector_type(4)));

__device__ inline unsigned short f2bf(float f) {
    unsigned int u = __float_as_uint(f);
    u += 0x7fffu + ((u >> 16) & 1u);   // round-to-nearest-even
    return (unsigned short)(u >> 16);
}

// pack two f32 -> bf16x2 by TRUNCATION, one v_perm_b32 (validated r7)
__device__ __forceinline__ unsigned pkbf_trunc(float lo, float hi) {
    return __builtin_amdgcn_perm(__float_as_uint(hi), __float_as_uint(lo), 0x07060302u);
}

// async global->LDS, 16 B per lane; LDS dest is wave-uniform base + lane*16
__device__ __forceinline__ void async16(const void* g, void* l) {
    __builtin_amdgcn_global_load_lds(
        (__attribute__((address_space(1))) void*)g,
        (__attribute__((address_space(3))) void*)l, 16, 0, 0);
}

// ---------------------------------------------------------------- fp32 -> bf16 weight casts (merged)
__global__ __launch_bounds__(256) void cvt_weights(const float* __restrict__ in_w,
                                                   const float* __restrict__ out_w,
                                                   unsigned short* __restrict__ wib,
                                                   unsigned short* __restrict__ wob) {
    const int N1 = 3 * EMBED * EMBED;
    int i = (blockIdx.x * 256 + threadIdx.x) * 4;
    const float* src; unsigned short* dst; int off;
    if (i < N1) { src = in_w;  dst = wib; off = i; }
    else        { src = out_w; dst = wob; off = i - N1; }
    float4 f = *(const float4*)(src + off);
    uint2 p;
    p.x = (unsigned)f2bf(f.x) | ((unsigned)f2bf(f.y) << 16);
    p.y = (unsigned)f2bf(f.z) | ((unsigned)f2bf(f.w) << 16);
    *(uint2*)(dst + off) = p;
}

// ---------------------------------------------------------------- LayerNorm -> bf16
__global__ __launch_bounds__(256) void ln_kernel(
    const float* __restrict__ feat, const float* __restrict__ g,
    const float* __restrict__ b, unsigned short* __restrict__ xln)
{
    int tid   = threadIdx.x;
    int token = blockIdx.x * 4 + (tid >> 6);
    int lane  = tid & 63;
    const float* row = feat + (size_t)token * EMBED;

    float x[8];
    *(float4*)(x)     = *(const float4*)(row + lane * 4);
    *(float4*)(x + 4) = *(const float4*)(row + 256 + lane * 4);

    float sum = 0.f, ssq = 0.f;
#pragma unroll
    for (int i = 0; i < 8; i++) { sum += x[i]; ssq += x[i] * x[i]; }
#pragma unroll
    for (int off = 32; off > 0; off >>= 1) {
        sum += __shfl_xor(sum, off, 64);
        ssq += __shfl_xor(ssq, off, 64);
    }
    float mu  = sum * (1.0f / EMBED);
    float var = ssq * (1.0f / EMBED) - mu * mu;
    float rs  = rsqrtf(var + LN_EPS);

    float gg[8], bb[8], o[8];
    *(float4*)(gg)     = *(const float4*)(g + lane * 4);
    *(float4*)(gg + 4) = *(const float4*)(g + 256 + lane * 4);
    *(float4*)(bb)     = *(const float4*)(b + lane * 4);
    *(float4*)(bb + 4) = *(const float4*)(b + 256 + lane * 4);
#pragma unroll
    for (int i = 0; i < 8; i++) o[i] = (x[i] - mu) * rs * gg[i] + bb[i];

    unsigned short* orow = xln + (size_t)token * EMBED;
    uint2 lo, hi;
    lo.x = pkbf_trunc(0, 0) * 0 + ((unsigned)f2bf(o[0]) | ((unsigned)f2bf(o[1]) << 16));
    lo.y = (unsigned)f2bf(o[2]) | ((unsigned)f2bf(o[3]) << 16);
    hi.x = (unsigned)f2bf(o[4]) | ((unsigned)f2bf(o[5]) << 16);
    hi.y = (unsigned)f2bf(o[6]) | ((unsigned)f2bf(o[7]) << 16);
    *(uint2*)(orow + lane * 4)       = lo;
    *(uint2*)(orow + 256 + lane * 4) = hi;
}

// ---------------------------------------------------------------- MFMA GEMM core
// 128x128 tile, 4 waves each 64x64, BK=64 (two stride-32 LDS pairs),
// global_load_lds x16, 32 MFMA per barrier-pair.
__device__ __forceinline__ void gemm_core(const unsigned short* __restrict__ A,
                                          const unsigned short* __restrict__ Bt,
                                          int i0, int j0,
                                          unsigned short (*As0)[32], unsigned short (*As1)[32],
                                          unsigned short (*Bs0)[32], unsigned short (*Bs1)[32],
                                          f32x4 acc[4][4])
{
    int t = threadIdx.x;
    int wave = t >> 6, lane = t & 63, quad = lane >> 4, l16 = lane & 15;
    int wm = (wave >> 1) * 64, wn = (wave & 1) * 64;
    int srow = t >> 2, scol = (t & 3) * 8;
    const unsigned short* ga0 = A  + (size_t)(i0 + srow) * EMBED + scol;
    const unsigned short* ga1 = A  + (size_t)(i0 + srow + 64) * EMBED + scol;
    const unsigned short* gb0 = Bt + (size_t)(j0 + srow) * EMBED + scol;
    const unsigned short* gb1 = Bt + (size_t)(j0 + srow + 64) * EMBED + scol;

    for (int k0 = 0; k0 < EMBED; k0 += 64) {
        __syncthreads();                    // prior-iter readers done
        async16(ga0 + k0,      &As0[srow][scol]);
        async16(ga1 + k0,      &As0[srow + 64][scol]);
        async16(gb0 + k0,      &Bs0[srow][scol]);
        async16(gb1 + k0,      &Bs0[srow + 64][scol]);
        async16(ga0 + k0 + 32, &As1[srow][scol]);
        async16(ga1 + k0 + 32, &As1[srow + 64][scol]);
        async16(gb0 + k0 + 32, &Bs1[srow][scol]);
        async16(gb1 + k0 + 32, &Bs1[srow + 64][scol]);
        __syncthreads();                    // barrier drains the DMA

#pragma unroll
        for (int h = 0; h < 2; h++) {
            unsigned short (*Ah)[32] = h ? As1 : As0;
            unsigned short (*Bh)[32] = h ? Bs1 : Bs0;
            bf16x8 af[4], bfr[4];
#pragma unroll
            for (int m = 0; m < 4; m++) af[m]  = *(const bf16x8*)&Ah[wm + m * 16 + l16][quad * 8];
#pragma unroll
            for (int n = 0; n < 4; n++) bfr[n] = *(const bf16x8*)&Bh[wn + n * 16 + l16][quad * 8];
#pragma unroll
            for (int m = 0; m < 4; m++)
#pragma unroll
                for (int n = 0; n < 4; n++)
                    acc[m][n] = __builtin_amdgcn_mfma_f32_16x16x32_bf16(af[m], bfr[n], acc[m][n], 0, 0, 0);
        }
    }
}

// ---------------------------------------------------------------- QKV GEMM (bf16 out, scatter)
// q,k,v all [bh][w][d]; 16 l16-lanes cover 32 contiguous B -> sector-clean.
// q pre-scaled by 0.125*log2(e) so attention can use exp2 directly.
__global__ __launch_bounds__(256) void qkv_gemm_mfma(
    const unsigned short* __restrict__ A, const unsigned short* __restrict__ Bt,
    const float* __restrict__ bias, unsigned short* __restrict__ qo,
    unsigned short* __restrict__ ko, unsigned short* __restrict__ vo)
{
    __shared__ unsigned short As0[128][32], As1[128][32];
    __shared__ unsigned short Bs0[128][32], Bs1[128][32];
    f32x4 acc[4][4];
    const f32x4 z = {0.f, 0.f, 0.f, 0.f};
#pragma unroll
    for (int m = 0; m < 4; m++)
#pragma unroll
        for (int n = 0; n < 4; n++) acc[m][n] = z;

    int i0 = blockIdx.x * 128, j0 = blockIdx.y * 128;
    gemm_core(A, Bt, i0, j0, As0, As1, Bs0, Bs1, acc);

    int t = threadIdx.x, wave = t >> 6, lane = t & 63, quad = lane >> 4, l16 = lane & 15;
    int wm = (wave >> 1) * 64, wn = (wave & 1) * 64;
    int seg = j0 >> 9;                       // tile lies wholly in one of q/k/v
    unsigned short* outp = (seg == 0) ? qo : ((seg == 1) ? ko : vo);
    float scale = (seg == 0) ? 0.18033688f : 1.0f;   // 0.125 * log2(e)

    float bj[4]; int hh[4], dd[4];
#pragma unroll
    for (int n = 0; n < 4; n++) {
        int j = j0 + wn + n * 16 + l16;
        bj[n] = bias[j];
        hh[n] = (j >> 6) & 7;
        dd[n] = j & 63;
    }
#pragma unroll
    for (int m = 0; m < 4; m++)
#pragma unroll
        for (int r = 0; r < 4; r++) {
            int token = i0 + wm + m * 16 + quad * 4 + r;
            int w  = token >> 4;
            int b_ = token & 15;
#pragma unroll
            for (int n = 0; n < 4; n++) {
                size_t idx = (((size_t)(b_ * NHEADS + hh[n]) * W_LEN + w) << 6) + dd[n];
                outp[idx] = f2bf((acc[m][n][r] + bj[n]) * scale);
            }
        }
}

// ---------------------------------------------------------------- out-proj GEMM + residual
__global__ __launch_bounds__(256) void out_gemm_mfma(
    const unsigned short* __restrict__ A, const unsigned short* __restrict__ Bt,
    const float* __restrict__ bias, const float* __restrict__ feat,
    float* __restrict__ out)
{
    __shared__ unsigned short As0[128][32], As1[128][32];
    __shared__ unsigned short Bs0[128][32], Bs1[128][32];
    f32x4 acc[4][4];
    const f32x4 z = {0.f, 0.f, 0.f, 0.f};
#pragma unroll
    for (int m = 0; m < 4; m++)
#pragma unroll
        for (int n = 0; n < 4; n++) acc[m][n] = z;

    int i0 = blockIdx.x * 128, j0 = blockIdx.y * 128;
    gemm_core(A, Bt, i0, j0, As0, As1, Bs0, Bs1, acc);

    int t = threadIdx.x, wave = t >> 6, lane = t & 63, quad = lane >> 4, l16 = lane & 15;
    int wm = (wave >> 1) * 64, wn = (wave & 1) * 64;

    float bj[4];
#pragma unroll
    for (int n = 0; n < 4; n++) bj[n] = bias[j0 + wn + n * 16 + l16];
#pragma unroll
    for (int m = 0; m < 4; m++)
#pragma unroll
        for (int r = 0; r < 4; r++) {
            int token = i0 + wm + m * 16 + quad * 4 + r;
#pragma unroll
            for (int n = 0; n < 4; n++) {
                int col = j0 + wn + n * 16 + l16;
                size_t idx = (size_t)token * EMBED + col;
                out[idx] = acc[m][n][r] + bj[n] + feat[idx];
            }
        }
}

// ---------------------------------------------------------------- flash attention, MFMA, S^T form
// grid = (bh=128, qtile=8): q-tiles of a bh colocate per XCD, K/V L2-resident.
// K staged cooperatively in LDS (global read ONCE per block per tile — the
// r7 per-wave global-fragment experiment thrashed L2: FETCH 30->138 MB),
// swizzled layout, register-prefetched one tile ahead. V transposed in-LDS
// via v_perm pair-pack. P/O packed to bf16 by v_perm truncation. Static
// softmax via exp2 (q pre-scaled by 0.125*log2e; scores bounded).
__global__ __launch_bounds__(256, 4) void attn_mfma(
    const unsigned short* __restrict__ q, const unsigned short* __restrict__ k,
    const unsigned short* __restrict__ v, unsigned short* __restrict__ outp)
{
    __shared__ union {
        unsigned short Q[128][72];                 // only during Q-frag hoist
        struct {
            unsigned short K[64][64];              // swizzled [kj][d]
            unsigned short V[64][72];              // [d][kj] (transposed in LDS)
            unsigned short P[4][32][72];           // per-wave P[qrow][kj]
        } s;
    } sm;

    int t = threadIdx.x, wave = t >> 6, lane = t & 63, quad = lane >> 4, l16 = lane & 15;
    int bh = blockIdx.x;
    int q0 = blockIdx.y * 128;
    const unsigned short* qp = q + ((size_t)bh * W_LEN + q0) * HEAD_DIM;
    const unsigned short* kp = k + (size_t)bh * W_LEN * HEAD_DIM;
    const unsigned short* vp = v + (size_t)bh * W_LEN * HEAD_DIM;

    // stage Q (128x64) then hoist this wave's Q B-frags into registers
    {
        int qr = t >> 1, qc0 = (t & 1) * 32;
#pragma unroll
        for (int c = 0; c < 32; c += 8)
            *(uint4*)&sm.Q[qr][qc0 + c] = *(const uint4*)(qp + (size_t)qr * 64 + qc0 + c);
    }
    __syncthreads();
    bf16x8 qf[2][2];                               // [nt][ks]
#pragma unroll
    for (int nt = 0; nt < 2; nt++)
#pragma unroll
        for (int ks = 0; ks < 2; ks++)
            qf[nt][ks] = *(const bf16x8*)&sm.Q[wave * 32 + nt * 16 + l16][ks * 32 + quad * 8];
    __syncthreads();                               // all waves done with Q region

    float l_st[2] = {0.f, 0.f};
    f32x4 o_acc[4][2];                             // [mtd(d)][nt(qrow)]
    const f32x4 z = {0.f, 0.f, 0.f, 0.f};
#pragma unroll
    for (int m = 0; m < 4; m++)
#pragma unroll
        for (int n = 0; n < 2; n++) o_acc[m][n] = z;

    unsigned short* kl = &sm.s.K[0][0];
    int sr = t >> 3;                                // K staging row 0..31
    int sc = ((t & 7) ^ (sr & 7)) * 8;              // swizzled chunk (ushorts)
    int j2 = t & 31, vc = (t >> 5) * 8;             // V staging: kj-pair, d-chunk

    // prefetch tile 0 into registers
    uint4 kg[2];
    union { uint4 u; unsigned w[4]; } vg0, vg1;
#pragma unroll
    for (int j = 0; j < 2; j++)
        kg[j] = *(const uint4*)(kp + (size_t)(sr + j * 32) * 64 + sc);
    vg0.u = *(const uint4*)(vp + (size_t)(2 * j2) * 64 + vc);
    vg1.u = *(const uint4*)(vp + (size_t)(2 * j2 + 1) * 64 + vc);

    for (int kt = 0; kt < W_LEN; kt += 64) {
        __syncthreads();                           // prior-iter K/V/P readers done
#pragma unroll
        for (int j = 0; j < 2; j++)
            *(uint4*)(kl + (size_t)(t + j * 256) * 8) = kg[j];
        // publish V^T[d][kj] via v_perm pair-pack (lossless repack)
#pragma unroll
        for (int w2 = 0; w2 < 4; w2++) {
            unsigned lo = __builtin_amdgcn_perm(vg1.w[w2], vg0.w[w2], 0x05040100u);
            unsigned hi = __builtin_amdgcn_perm(vg1.w[w2], vg0.w[w2], 0x07060302u);
            *(unsigned*)&sm.s.V[vc + 2 * w2][2 * j2]     = lo;
            *(unsigned*)&sm.s.V[vc + 2 * w2 + 1][2 * j2] = hi;
        }
        __syncthreads();

        // prefetch next tile (clamped; overlaps with the MFMA section below)
        int ktn = (kt + 64 < W_LEN) ? kt + 64 : kt;
#pragma unroll
        for (int j = 0; j < 2; j++)
            kg[j] = *(const uint4*)(kp + (size_t)(ktn + sr + j * 32) * 64 + sc);
        vg0.u = *(const uint4*)(vp + (size_t)(ktn + 2 * j2) * 64 + vc);
        vg1.u = *(const uint4*)(vp + (size_t)(ktn + 2 * j2 + 1) * 64 + vc);

        // ---- S^T = K * Q^T : s[mt][nt], rows=kj, cols=qrow
        f32x4 s[4][2];
#pragma unroll
        for (int mt = 0; mt < 4; mt++)
#pragma unroll
            for (int nt = 0; nt < 2; nt++) s[mt][nt] = z;
#pragma unroll
        for (int ks = 0; ks < 2; ks++) {
            int swz = (((ks * 4 + quad) ^ (l16 & 7)) * 8);
            bf16x8 kf[4];
#pragma unroll
            for (int mt = 0; mt < 4; mt++)
                kf[mt] = *(const bf16x8*)(kl + (size_t)(mt * 16 + l16) * 64 + swz);
#pragma unroll
            for (int mt = 0; mt < 4; mt++)
#pragma unroll
                for (int nt = 0; nt < 2; nt++)
                    s[mt][nt] = __builtin_amdgcn_mfma_f32_16x16x32_bf16(kf[mt], qf[nt][ks], s[mt][nt], 0, 0, 0);
        }

        // ---- static softmax: p = 2^s (q pre-scaled by log2e), row-sum
#pragma unroll
        for (int nt = 0; nt < 2; nt++) {
            float sum = 0.f;
#pragma unroll
            for (int mt = 0; mt < 4; mt++)
#pragma unroll
                for (int r = 0; r < 4; r++) {
                    float p = exp2f(s[mt][nt][r]);
                    s[mt][nt][r] = p;
                    sum += p;
                }
            sum += __shfl_xor(sum, 16, 64);
            sum += __shfl_xor(sum, 32, 64);
            l_st[nt] += sum;
        }

        // ---- P -> LDS row-major [qrow][kj]; v_perm truncation packs
#pragma unroll
        for (int nt = 0; nt < 2; nt++)
#pragma unroll
            for (int mt = 0; mt < 4; mt++) {
                uint2 pk;
                pk.x = pkbf_trunc(s[mt][nt][0], s[mt][nt][1]);
                pk.y = pkbf_trunc(s[mt][nt][2], s[mt][nt][3]);
                *(uint2*)&sm.s.P[wave][nt * 16 + l16][mt * 16 + quad * 4] = pk;
            }
        asm volatile("s_waitcnt lgkmcnt(0)" ::: "memory");   // wave-private P

        // ---- O^T += V^T * P^T
#pragma unroll
        for (int ks = 0; ks < 2; ks++) {
            bf16x8 vf[4], pf[2];
#pragma unroll
            for (int mtd = 0; mtd < 4; mtd++)
                vf[mtd] = *(const bf16x8*)&sm.s.V[mtd * 16 + l16][ks * 32 + quad * 8];
#pragma unroll
            for (int nt = 0; nt < 2; nt++)
                pf[nt] = *(const bf16x8*)&sm.s.P[wave][nt * 16 + l16][ks * 32 + quad * 8];
#pragma unroll
            for (int mtd = 0; mtd < 4; mtd++)
#pragma unroll
                for (int nt = 0; nt < 2; nt++)
                    o_acc[mtd][nt] = __builtin_amdgcn_mfma_f32_16x16x32_bf16(vf[mtd], pf[nt], o_acc[mtd][nt], 0, 0, 0);
        }
    }

    // ---- epilogue: O^T cols=qrow (lane), rows=d (regs): uint2 stores
    int b_ = bh >> 3, h = bh & 7;
#pragma unroll
    for (int nt = 0; nt < 2; nt++) {
        int w = q0 + wave * 32 + nt * 16 + l16;
        int token = w * BSZ + b_;
        float inv = 1.0f / l_st[nt];
#pragma unroll
        for (int mtd = 0; mtd < 4; mtd++) {
            uint2 pk;
            pk.x = pkbf_trunc(o_acc[mtd][nt][0] * inv, o_acc[mtd][nt][1] * inv);
            pk.y = pkbf_trunc(o_acc[mtd][nt][2] * inv, o_acc[mtd][nt][3] * inv);
            *(uint2*)(outp + (size_t)token * EMBED + h * HEAD_DIM + mtd * 16 + quad * 4) = pk;
        }
    }
}

// ---------------------------------------------------------------- launch
extern "C" void kernel_launch(void* const* d_in, const int* in_sizes, int n_in,
                              void* d_out, int out_size, void* d_ws, size_t ws_size,
                              hipStream_t stream) {
    const float* feat  = (const float*)d_in[0];
    const float* in_w  = (const float*)d_in[1];
    const float* in_b  = (const float*)d_in[2];
    const float* out_w = (const float*)d_in[3];
    const float* out_b = (const float*)d_in[4];
    const float* ln_g  = (const float*)d_in[5];
    const float* ln_b  = (const float*)d_in[6];
    float* out = (float*)d_out;

    char* ws = (char*)d_ws;
    const size_t SZB = (size_t)TOKENS * EMBED * sizeof(unsigned short);   // 16.8 MB
    unsigned short* xln = (unsigned short*)ws;
    unsigned short* qb  = (unsigned short*)(ws + SZB);
    unsigned short* kb  = (unsigned short*)(ws + 2 * SZB);
    unsigned short* vb  = (unsigned short*)(ws + 3 * SZB);
    unsigned short* ao  = (unsigned short*)(ws + 4 * SZB);
    unsigned short* wib = (unsigned short*)(ws + 5 * SZB);
    unsigned short* wob = (unsigned short*)(ws + 5 * SZB +
                                            (size_t)3 * EMBED * EMBED * sizeof(unsigned short));

    cvt_weights<<<(4 * EMBED * EMBED) / 1024, 256, 0, stream>>>(in_w, out_w, wib, wob);
    ln_kernel<<<TOKENS / 4, 256, 0, stream>>>(feat, ln_g, ln_b, xln);
    qkv_gemm_mfma<<<dim3(TOKENS / 128, (3 * EMBED) / 128), 256, 0, stream>>>(
        xln, wib, in_b, qb, kb, vb);
    attn_mfma<<<dim3(BSZ * NHEADS, W_LEN / 128), 256, 0, stream>>>(qb, kb, vb, ao);
    out_gemm_mfma<<<dim3(TOKENS / 128, EMBED / 128), 256, 0, stream>>>(
        ao, wob, out_b, feat, out);
}